// Round 1
// baseline (43.572 us; speedup 1.0000x reference)
//
#include <hip/hip_runtime.h>
#include <math.h>

#define G_N 1024
#define C_N 17
#define NX 200
#define NY 200
#define NZ 16
#define N_VOX (NX * NY * NZ)
#define MAHA_T 7.5f

// Packed per-gaussian params in d_ws: 16 floats each.
// [0..2]=mu, [3]=op, [4..6]=a00,a11,a22, [7..9]=2*a01,2*a02,2*a12,
// [10..12]=AABB half extents, [13..15]=pad
__global__ void gv_prep_kernel(const float* __restrict__ means,
                               const float* __restrict__ ops,
                               const float* __restrict__ covs,
                               float* __restrict__ gp) {
    int g = blockIdx.x * blockDim.x + threadIdx.x;
    if (g >= G_N) return;
    const float* cv = covs + g * 9;
    double c00 = cv[0], c01 = cv[1], c02 = cv[2];
    double c11 = cv[4], c12 = cv[5], c22 = cv[8];
    double m00 = c11 * c22 - c12 * c12;
    double m01 = c02 * c12 - c01 * c22;
    double m02 = c01 * c12 - c02 * c11;
    double det = c00 * m00 + c01 * m01 + c02 * m02;
    double inv = 1.0 / det;
    float a00 = (float)(m00 * inv);
    float a01 = (float)(m01 * inv);
    float a02 = (float)(m02 * inv);
    float a11 = (float)((c00 * c22 - c02 * c02) * inv);
    float a12 = (float)((c02 * c01 - c00 * c12) * inv);
    float a22 = (float)((c00 * c11 - c01 * c01) * inv);
    float* o = gp + g * 16;
    o[0] = means[g * 3 + 0];
    o[1] = means[g * 3 + 1];
    o[2] = means[g * 3 + 2];
    o[3] = ops[g];
    o[4] = a00; o[5] = a11; o[6] = a22;
    o[7] = 2.f * a01; o[8] = 2.f * a02; o[9] = 2.f * a12;
    // conservative ellipsoid AABB half-extents: sqrt(T * cov_ii), padded
    o[10] = sqrtf(MAHA_T * (float)c00) * 1.01f + 0.01f;
    o[11] = sqrtf(MAHA_T * (float)c11) * 1.01f + 0.01f;
    o[12] = sqrtf(MAHA_T * (float)c22) * 1.01f + 0.01f;
    o[13] = 0.f; o[14] = 0.f; o[15] = 0.f;
}

// One block = 4(x) x 4(y) x 16(z) voxel tile, 256 threads, 1 voxel/thread.
__launch_bounds__(256)
__global__ void gv_splat_kernel(const float* __restrict__ coords,
                                const float* __restrict__ feats,
                                const float* __restrict__ gp,
                                float* __restrict__ dens_out,
                                float* __restrict__ feat_out) {
    __shared__ int s_count;
    __shared__ unsigned short s_list[G_N];

    const int tid = threadIdx.x;
    const int bx = blockIdx.x, by = blockIdx.y;

    // Block AABB in world coords (tile 1.6m x 1.6m x full z)
    const float x0 = -40.f + (float)(bx * 4) * 0.4f;
    const float x1 = x0 + 1.6f;
    const float y0 = -40.f + (float)(by * 4) * 0.4f;
    const float y1 = y0 + 1.6f;
    const float z0 = -1.f, z1 = 5.4f;

    // Deterministic compaction by wave 0 (ballot scan, ascending g order).
    if (tid < 64) {
        int base = 0;
        for (int r = 0; r < G_N / 64; ++r) {
            int g = r * 64 + tid;
            const float* p = gp + g * 16;
            float mx = p[0], my = p[1], mz = p[2];
            float hx = p[10], hy = p[11], hz = p[12];
            bool hit = (mx - hx <= x1) && (mx + hx >= x0) &&
                       (my - hy <= y1) && (my + hy >= y0) &&
                       (mz - hz <= z1) && (mz + hz >= z0);
            unsigned long long m = __ballot(hit);
            int rank = __popcll(m & ((1ull << tid) - 1ull));
            if (hit) s_list[base + rank] = (unsigned short)g;
            base += __popcll(m);
        }
        if (tid == 0) s_count = base;
    }
    __syncthreads();
    const int ng = s_count;

    // Voxel owned by this thread
    const int z = tid & 15;
    const int y = (tid >> 4) & 3;
    const int x = tid >> 6;
    const int X = bx * 4 + x;
    const int Y = by * 4 + y;
    const int n = z + NZ * (Y + NY * X);

    const float cx = coords[n * 3 + 0];
    const float cy = coords[n * 3 + 1];
    const float cz = coords[n * 3 + 2];

    float dsum = 0.f, cntf = 0.f;
    float fsum[C_N];
#pragma unroll
    for (int c = 0; c < C_N; ++c) fsum[c] = 0.f;

    for (int i = 0; i < ng; ++i) {
        int g = __builtin_amdgcn_readfirstlane((int)s_list[i]);
        const float* p = gp + g * 16;
        float mx = p[0], my = p[1], mz = p[2], op = p[3];
        float a00 = p[4], a11 = p[5], a22 = p[6];
        float b01 = p[7], b02 = p[8], b12 = p[9];
        float d0 = cx - mx, d1 = cy - my, d2 = cz - mz;
        float u = fmaf(a00, d0, fmaf(b01, d1, b02 * d2));
        float v = fmaf(a11, d1, b12 * d2);
        float w = a22 * d2;
        float maha = fmaf(d0, u, fmaf(d1, v, d2 * w));
        if (maha <= MAHA_T) {
            dsum += op * __expf(-0.5f * maha);
            cntf += 1.f;
            const float* ft = feats + g * C_N;
#pragma unroll
            for (int c = 0; c < C_N; ++c) fsum[c] = fmaf(op, ft[c], fsum[c]);
        }
    }

    float denom = fmaxf(cntf, 1.f);
    dens_out[n] = dsum / denom;
    float* fo = feat_out + (long)n * C_N;
#pragma unroll
    for (int c = 0; c < C_N; ++c) fo[c] = fsum[c] / denom;
}

extern "C" void kernel_launch(void* const* d_in, const int* in_sizes, int n_in,
                              void* d_out, int out_size, void* d_ws, size_t ws_size,
                              hipStream_t stream) {
    const float* grid_coords = (const float*)d_in[0];  // [N,3]
    const float* means3d     = (const float*)d_in[1];  // [1,G,3]
    const float* opacities   = (const float*)d_in[2];  // [1,G,1]
    const float* features    = (const float*)d_in[3];  // [1,G,C]
    const float* covariances = (const float*)d_in[4];  // [1,G,3,3]

    float* dens_out = (float*)d_out;             // [N]
    float* feat_out = (float*)d_out + N_VOX;     // [N,C]
    float* gp = (float*)d_ws;                    // G*16 floats = 64KB

    gv_prep_kernel<<<(G_N + 255) / 256, 256, 0, stream>>>(means3d, opacities,
                                                          covariances, gp);
    dim3 grid(NX / 4, NY / 4);
    gv_splat_kernel<<<grid, 256, 0, stream>>>(grid_coords, features, gp,
                                              dens_out, feat_out);
}

// Round 2
// 38.624 us; speedup vs baseline: 1.1281x; 1.1281x over previous
//
#include <hip/hip_runtime.h>
#include <math.h>

#define G_N 1024
#define C_N 17
#define NX 200
#define NY 200
#define NZ 16
#define N_VOX (NX * NY * NZ)
#define MAHA_T 7.5f

// d_ws layout:
//   gp:   G_N*16 floats (64 KB): mu(3), op, a00,a11,a22, 2a01,2a02,2a12, pad(6)
//   cull: G_N float4   (16 KB): xlo, xhi, ylo, yhi  (xlo=+BIG if z-rejected)

__global__ void gv_prep_kernel(const float* __restrict__ means,
                               const float* __restrict__ ops,
                               const float* __restrict__ covs,
                               float* __restrict__ gp,
                               float4* __restrict__ cull) {
    int g = blockIdx.x * blockDim.x + threadIdx.x;
    if (g >= G_N) return;
    const float* cv = covs + g * 9;
    double c00 = cv[0], c01 = cv[1], c02 = cv[2];
    double c11 = cv[4], c12 = cv[5], c22 = cv[8];
    double m00 = c11 * c22 - c12 * c12;
    double m01 = c02 * c12 - c01 * c22;
    double m02 = c01 * c12 - c02 * c11;
    double det = c00 * m00 + c01 * m01 + c02 * m02;
    double inv = 1.0 / det;
    float a00 = (float)(m00 * inv);
    float a01 = (float)(m01 * inv);
    float a02 = (float)(m02 * inv);
    float a11 = (float)((c00 * c22 - c02 * c02) * inv);
    float a12 = (float)((c02 * c01 - c00 * c12) * inv);
    float a22 = (float)((c00 * c11 - c01 * c01) * inv);
    float mx = means[g * 3 + 0], my = means[g * 3 + 1], mz = means[g * 3 + 2];
    float* o = gp + g * 16;
    o[0] = mx; o[1] = my; o[2] = mz;
    o[3] = ops[g];
    o[4] = a00; o[5] = a11; o[6] = a22;
    o[7] = 2.f * a01; o[8] = 2.f * a02; o[9] = 2.f * a12;
    o[10] = 0.f; o[11] = 0.f; o[12] = 0.f;
    o[13] = 0.f; o[14] = 0.f; o[15] = 0.f;
    // conservative ellipsoid AABB half-extents: sqrt(T * cov_ii), padded
    float hx = sqrtf(MAHA_T * (float)c00) * 1.01f + 0.01f;
    float hy = sqrtf(MAHA_T * (float)c11) * 1.01f + 0.01f;
    float hz = sqrtf(MAHA_T * (float)c22) * 1.01f + 0.01f;
    bool zok = (mz - hz <= 5.4f) && (mz + hz >= -1.0f);
    float4 cb;
    cb.x = zok ? (mx - hx) : 3.0e38f;   // empty interval if z-rejected
    cb.y = mx + hx;
    cb.z = my - hy;
    cb.w = my + hy;
    cull[g] = cb;
}

// One block = 4(x) x 4(y) x 16(z) voxel tile, 256 threads, 1 voxel/thread.
__launch_bounds__(256, 4)
__global__ void gv_splat_kernel(const float* __restrict__ feats,
                                const float* __restrict__ gp,
                                const float4* __restrict__ cull,
                                float* __restrict__ dens_out,
                                float* __restrict__ feat_out) {
    __shared__ unsigned short s_stage[G_N];
    __shared__ unsigned short s_list[G_N];
    __shared__ int s_wcnt[4];

    const int tid = threadIdx.x;
    const int wave = tid >> 6;
    const int lane = tid & 63;
    const int bx = blockIdx.x, by = blockIdx.y;

    // Block AABB in world coords (tile 1.6m x 1.6m x full z)
    const float x0 = -40.f + (float)(bx * 4) * 0.4f;
    const float x1 = x0 + 1.6f;
    const float y0 = -40.f + (float)(by * 4) * 0.4f;
    const float y1 = y0 + 1.6f;

    // 4-wave parallel cull: wave w handles g in [256w, 256w+256), 4 rounds.
    // Local order within each wave's range is ascending-g (deterministic).
    int base = 0;
#pragma unroll
    for (int r = 0; r < 4; ++r) {
        int g = wave * 256 + r * 64 + lane;
        float4 cb = cull[g];
        bool hit = (cb.x <= x1) && (cb.y >= x0) && (cb.z <= y1) && (cb.w >= y0);
        unsigned long long m = __ballot(hit);
        int rank = __popcll(m & ((1ull << lane) - 1ull));
        if (hit) s_stage[wave * 256 + base + rank] = (unsigned short)g;
        base += __popcll(m);
    }
    if (lane == 0) s_wcnt[wave] = base;
    __syncthreads();
    const int c0 = s_wcnt[0], c1 = s_wcnt[1], c2 = s_wcnt[2], c3 = s_wcnt[3];
    const int total = c0 + c1 + c2 + c3;
    int off = 0;
    if (wave > 0) off += c0;
    if (wave > 1) off += c1;
    if (wave > 2) off += c2;
    for (int i = lane; i < base; i += 64)
        s_list[off + i] = s_stage[wave * 256 + i];
    __syncthreads();

    // Voxel owned by this thread
    const int z = tid & 15;
    const int yv = (tid >> 4) & 3;
    const int xv = tid >> 6;
    const int X = bx * 4 + xv;
    const int Y = by * 4 + yv;
    const int n = z + NZ * (Y + NY * X);

    // Coordinates computed to bit-match the reference:
    // (i + 0.5f) * 0.4f + lo   with separate mul/add roundings (no fma fuse).
    float cx, cy, cz;
    {
#pragma clang fp contract(off)
        cx = ((float)X + 0.5f) * 0.4f + -40.0f;
        cy = ((float)Y + 0.5f) * 0.4f + -40.0f;
        cz = ((float)z + 0.5f) * 0.4f + -1.0f;
    }

    float dsum = 0.f, cntf = 0.f;
    float fsum[C_N];
#pragma unroll
    for (int c = 0; c < C_N; ++c) fsum[c] = 0.f;

    for (int i = 0; i < total; ++i) {
        const int g = __builtin_amdgcn_readfirstlane((int)s_list[i]);
        const float* p = gp + (g << 4);   // uniform address -> scalar loads
        const float mx = p[0], my = p[1], mz = p[2], op = p[3];
        const float a00 = p[4], a11 = p[5], a22 = p[6];
        const float b01 = p[7], b02 = p[8], b12 = p[9];
        const float d0 = cx - mx, d1 = cy - my, d2 = cz - mz;
        const float u = fmaf(a00, d0, fmaf(b01, d1, b02 * d2));
        const float v = fmaf(a11, d1, b12 * d2);
        const float w = a22 * d2;
        const float maha = fmaf(d0, u, fmaf(d1, v, d2 * w));
        if (maha <= MAHA_T) {
            dsum = fmaf(op, __expf(-0.5f * maha), dsum);
            cntf += 1.f;
            const float* ft = feats + g * C_N;   // uniform -> scalar loads
#pragma unroll
            for (int c = 0; c < C_N; ++c) fsum[c] = fmaf(op, ft[c], fsum[c]);
        }
    }

    const float rd = 1.0f / fmaxf(cntf, 1.f);
    dens_out[n] = dsum * rd;
    float* fo = feat_out + (long)n * C_N;
#pragma unroll
    for (int c = 0; c < C_N; ++c) fo[c] = fsum[c] * rd;
}

extern "C" void kernel_launch(void* const* d_in, const int* in_sizes, int n_in,
                              void* d_out, int out_size, void* d_ws, size_t ws_size,
                              hipStream_t stream) {
    const float* means3d     = (const float*)d_in[1];  // [1,G,3]
    const float* opacities   = (const float*)d_in[2];  // [1,G,1]
    const float* features    = (const float*)d_in[3];  // [1,G,C]
    const float* covariances = (const float*)d_in[4];  // [1,G,3,3]

    float* dens_out = (float*)d_out;             // [N]
    float* feat_out = (float*)d_out + N_VOX;     // [N,C]
    float* gp   = (float*)d_ws;                  // G*16 floats = 64KB
    float4* cull = (float4*)((float*)d_ws + G_N * 16);  // G*4 floats = 16KB

    gv_prep_kernel<<<(G_N + 255) / 256, 256, 0, stream>>>(means3d, opacities,
                                                          covariances, gp, cull);
    dim3 grid(NX / 4, NY / 4);
    gv_splat_kernel<<<grid, 256, 0, stream>>>(features, gp, cull,
                                              dens_out, feat_out);
}

// Round 3
// 26.433 us; speedup vs baseline: 1.6484x; 1.4612x over previous
//
#include <hip/hip_runtime.h>
#include <math.h>

#define G_N 1024
#define C_N 17
#define NX 200
#define NY 200
#define NZ 16
#define N_VOX (NX * NY * NZ)
#define MAHA_T 7.5f
#define CHUNK 64

// d_ws layout:
//   gp:   G_N rows of 32 floats (128 B each, 128 KB total):
//         [0..2]=mu, [3]=op, [4..6]=a00,a11,a22, [7]=2a01, [8]=2a02, [9]=2a12,
//         [10]=pf0, [11]=pf1, [12..27]=pf2..pf16,pad   (pf = op*feature)
//   cull: G_N float4 (16 KB): xlo, xhi, ylo, yhi  (xlo=+BIG if z-rejected)

__global__ void gv_prep_kernel(const float* __restrict__ means,
                               const float* __restrict__ ops,
                               const float* __restrict__ feats,
                               const float* __restrict__ covs,
                               float4* __restrict__ gp4,
                               float4* __restrict__ cull) {
    int g = blockIdx.x * blockDim.x + threadIdx.x;
    if (g >= G_N) return;
    const float* cv = covs + g * 9;
    double c00 = cv[0], c01 = cv[1], c02 = cv[2];
    double c11 = cv[4], c12 = cv[5], c22 = cv[8];
    double m00 = c11 * c22 - c12 * c12;
    double m01 = c02 * c12 - c01 * c22;
    double m02 = c01 * c12 - c02 * c11;
    double det = c00 * m00 + c01 * m01 + c02 * m02;
    double inv = 1.0 / det;
    float a00 = (float)(m00 * inv);
    float a01 = (float)(m01 * inv);
    float a02 = (float)(m02 * inv);
    float a11 = (float)((c00 * c22 - c02 * c02) * inv);
    float a12 = (float)((c02 * c01 - c00 * c12) * inv);
    float a22 = (float)((c00 * c11 - c01 * c01) * inv);
    float mx = means[g * 3 + 0], my = means[g * 3 + 1], mz = means[g * 3 + 2];
    float op = ops[g];
    const float* ft = feats + g * C_N;
    float pf[C_N];
#pragma unroll
    for (int c = 0; c < C_N; ++c) pf[c] = op * ft[c];

    float4* o = gp4 + g * 8;
    o[0] = make_float4(mx, my, mz, op);
    o[1] = make_float4(a00, a11, a22, 2.f * a01);
    o[2] = make_float4(2.f * a02, 2.f * a12, pf[0], pf[1]);
    o[3] = make_float4(pf[2], pf[3], pf[4], pf[5]);
    o[4] = make_float4(pf[6], pf[7], pf[8], pf[9]);
    o[5] = make_float4(pf[10], pf[11], pf[12], pf[13]);
    o[6] = make_float4(pf[14], pf[15], pf[16], 0.f);
    o[7] = make_float4(0.f, 0.f, 0.f, 0.f);

    // conservative ellipsoid AABB half-extents: sqrt(T * cov_ii), padded
    float hx = sqrtf(MAHA_T * (float)c00) * 1.01f + 0.01f;
    float hy = sqrtf(MAHA_T * (float)c11) * 1.01f + 0.01f;
    float hz = sqrtf(MAHA_T * (float)c22) * 1.01f + 0.01f;
    bool zok = (mz - hz <= 5.4f) && (mz + hz >= -1.0f);
    float4 cb;
    cb.x = zok ? (mx - hx) : 3.0e38f;   // empty interval if z-rejected
    cb.y = mx + hx;
    cb.z = my - hy;
    cb.w = my + hy;
    cull[g] = cb;
}

// One block = 4(x) x 4(y) x 16(z) voxel tile, 256 threads, 1 voxel/thread.
__launch_bounds__(256, 4)
__global__ void gv_splat_kernel(const float4* __restrict__ gp4,
                                const float4* __restrict__ cull,
                                float* __restrict__ dens_out,
                                float* __restrict__ feat_out) {
    // Region A (17408 B) is time-multiplexed:
    //   phase 1 (cull):      ushort s_stage[1024]        (first 2 KB)
    //   phase 2 (main loop): float4 chunk stage [64*8]   (first 8 KB)
    //   phase 3 (epilogue):  float  s_fout[4][64*17]     (all 17408 B)
    __shared__ __align__(16) char smemA[4 * 64 * C_N * 4];
    __shared__ unsigned short s_list[G_N];
    __shared__ int s_wcnt[4];

    const int tid = threadIdx.x;
    const int wave = tid >> 6;
    const int lane = tid & 63;
    const int bx = blockIdx.x, by = blockIdx.y;

    // Block AABB in world coords (tile 1.6m x 1.6m x full z)
    const float x0 = -40.f + (float)(bx * 4) * 0.4f;
    const float x1 = x0 + 1.6f;
    const float y0 = -40.f + (float)(by * 4) * 0.4f;
    const float y1 = y0 + 1.6f;

    // 4-wave parallel cull: wave w handles g in [256w, 256w+256), 4 rounds.
    unsigned short* s_stage = (unsigned short*)smemA;
    int base = 0;
#pragma unroll
    for (int r = 0; r < 4; ++r) {
        int g = wave * 256 + r * 64 + lane;
        float4 cb = cull[g];
        bool hit = (cb.x <= x1) && (cb.y >= x0) && (cb.z <= y1) && (cb.w >= y0);
        unsigned long long m = __ballot(hit);
        int rank = __popcll(m & ((1ull << lane) - 1ull));
        if (hit) s_stage[wave * 256 + base + rank] = (unsigned short)g;
        base += __popcll(m);
    }
    if (lane == 0) s_wcnt[wave] = base;
    __syncthreads();
    const int c0 = s_wcnt[0], c1 = s_wcnt[1], c2 = s_wcnt[2], c3 = s_wcnt[3];
    const int total = c0 + c1 + c2 + c3;
    int off = 0;
    if (wave > 0) off += c0;
    if (wave > 1) off += c1;
    if (wave > 2) off += c2;
    for (int i = lane; i < base; i += 64)              // wave-local read of s_stage
        s_list[off + i] = s_stage[wave * 256 + i];

    // Voxel owned by this thread
    const int z = tid & 15;
    const int yv = (tid >> 4) & 3;
    const int xv = tid >> 6;
    const int X = bx * 4 + xv;
    const int Y = by * 4 + yv;
    const int n = z + NZ * (Y + NY * X);

    // Coordinates bit-matching the reference: separate mul/add roundings.
    float cx, cy, cz;
    {
#pragma clang fp contract(off)
        cx = ((float)X + 0.5f) * 0.4f + -40.0f;
        cy = ((float)Y + 0.5f) * 0.4f + -40.0f;
        cz = ((float)z + 0.5f) * 0.4f + -1.0f;
    }

    float dsum = 0.f, cntf = 0.f;
    float fsum[C_N];
#pragma unroll
    for (int c = 0; c < C_N; ++c) fsum[c] = 0.f;

    // Chunked main loop: bulk-stage candidate rows into LDS, then LDS-only math.
    float4* s_gd = (float4*)smemA;
    for (int cb = 0; cb < total; cb += CHUNK) {
        const int nc = min(CHUNK, total - cb);
        __syncthreads();   // region A free (prev chunk consumed / s_stage copied)
        for (int k = tid; k < nc * 8; k += 256) {
            int row = k >> 3, sub = k & 7;
            int g = (int)s_list[cb + row];
            s_gd[k] = gp4[g * 8 + sub];
        }
        __syncthreads();
        for (int j = 0; j < nc; ++j) {
            const float4* rowp = s_gd + j * 8;
            float4 q0 = rowp[0], q1 = rowp[1], q2 = rowp[2];
            float d0 = cx - q0.x, d1 = cy - q0.y, d2 = cz - q0.z;
            float u = fmaf(q1.x, d0, fmaf(q1.w, d1, q2.x * d2));
            float v = fmaf(q1.y, d1, q2.y * d2);
            float w = q1.z * d2;
            float maha = fmaf(d0, u, fmaf(d1, v, d2 * w));
            if (maha <= MAHA_T) {
                dsum = fmaf(q0.w, __expf(-0.5f * maha), dsum);
                cntf += 1.f;
                float4 q3 = rowp[3], q4 = rowp[4], q5 = rowp[5], q6 = rowp[6];
                fsum[0] += q2.z;  fsum[1] += q2.w;
                fsum[2] += q3.x;  fsum[3] += q3.y;  fsum[4] += q3.z;  fsum[5] += q3.w;
                fsum[6] += q4.x;  fsum[7] += q4.y;  fsum[8] += q4.z;  fsum[9] += q4.w;
                fsum[10] += q5.x; fsum[11] += q5.y; fsum[12] += q5.z; fsum[13] += q5.w;
                fsum[14] += q6.x; fsum[15] += q6.y; fsum[16] += q6.z;
            }
        }
    }
    __syncthreads();   // all waves done reading region A

    // Epilogue: coalesced writes.
    const float rd = 1.0f / fmaxf(cntf, 1.f);
    dens_out[n] = dsum * rd;            // 64 consecutive addrs per wave

    // Wave-local transpose through LDS (no barrier needed: same-wave ds order).
    float* fw = (float*)smemA + wave * (64 * C_N);
#pragma unroll
    for (int c = 0; c < C_N; ++c) fw[lane * C_N + c] = fsum[c] * rd;  // stride 17: conflict-free

    const long n0 = (long)NZ * ((long)by * 4 + (long)NY * X);  // first voxel of this wave's x-row
    float4* gout = (float4*)(feat_out + n0 * C_N);             // 16B-aligned (n0 % 16 == 0)
    const float4* lsrc = (const float4*)fw;
#pragma unroll
    for (int r = 0; r < 4; ++r) gout[lane + 64 * r] = lsrc[lane + 64 * r];
    if (lane < 16) gout[256 + lane] = lsrc[256 + lane];        // 272 float4 = 64*17 floats
}

extern "C" void kernel_launch(void* const* d_in, const int* in_sizes, int n_in,
                              void* d_out, int out_size, void* d_ws, size_t ws_size,
                              hipStream_t stream) {
    const float* means3d     = (const float*)d_in[1];  // [1,G,3]
    const float* opacities   = (const float*)d_in[2];  // [1,G,1]
    const float* features    = (const float*)d_in[3];  // [1,G,C]
    const float* covariances = (const float*)d_in[4];  // [1,G,3,3]

    float* dens_out = (float*)d_out;             // [N]
    float* feat_out = (float*)d_out + N_VOX;     // [N,C]
    float4* gp4  = (float4*)d_ws;                              // 128 KB
    float4* cull = (float4*)((char*)d_ws + G_N * 128);         // 16 KB

    gv_prep_kernel<<<(G_N + 255) / 256, 256, 0, stream>>>(means3d, opacities,
                                                          features, covariances,
                                                          gp4, cull);
    dim3 grid(NX / 4, NY / 4);
    gv_splat_kernel<<<grid, 256, 0, stream>>>(gp4, cull, dens_out, feat_out);
}

// Round 7
// 21.481 us; speedup vs baseline: 2.0285x; 1.2305x over previous
//
#include <hip/hip_runtime.h>
#include <math.h>

#define G_N 1024
#define C_N 17
#define NX 200
#define NY 200
#define NZ 16
#define N_VOX (NX * NY * NZ)
#define MAHA_T 7.5f
#define CAP 256   // max staged candidates per chunk (loop handles overflow)

// Single fused kernel. Tile = 8(x) x 8(y) x 16(z) = 1024 voxels.
// 512 threads: wave = x column, lane = (yv,z); each thread owns voxels
// (X, Y0, z) and (X, Y0+4, z).
__launch_bounds__(512)
__global__ void gv_fused_kernel(const float* __restrict__ means,
                                const float* __restrict__ ops,
                                const float* __restrict__ feats,
                                const float* __restrict__ covs,
                                float* __restrict__ dens_out,
                                float* __restrict__ feat_out) {
    // Region A (34816 B), time-multiplexed:
    //   phase 1 (cull):     ushort s_stage[1024]            (2 KB)
    //   phase 2 (main):     float4 rows[CAP][8]             (32 KB)
    //   phase 3 (epilogue): per-wave out-stage 8 x 4352 B   (34816 B)
    __shared__ __align__(16) char smemA[8 * 64 * C_N * 4];
    __shared__ unsigned short s_list[G_N];
    __shared__ int s_wcnt[8];

    const int tid = threadIdx.x;
    const int wave = tid >> 6;
    const int lane = tid & 63;
    const int bx = blockIdx.x, by = blockIdx.y;

    // Block AABB (3.2m x 3.2m x full z)
    const float x0 = -40.f + (float)(bx * 8) * 0.4f;
    const float x1 = x0 + 3.2f;
    const float y0 = -40.f + (float)(by * 8) * 0.4f;
    const float y1 = y0 + 3.2f;

    // ---- Phase 1: 8-wave parallel cull from raw inputs (2 rounds/wave) ----
    unsigned short* s_stage = (unsigned short*)smemA;
    int base = 0;
#pragma unroll
    for (int r = 0; r < 2; ++r) {
        int g = wave * 128 + r * 64 + lane;
        float mx = means[3 * g], my = means[3 * g + 1], mz = means[3 * g + 2];
        float c00 = covs[9 * g], c11 = covs[9 * g + 4], c22 = covs[9 * g + 8];
        // exact ellipsoid AABB half-extent is sqrt(T*cov_ii); pad for fp safety
        float hx = sqrtf(MAHA_T * c00) * 1.01f + 0.01f;
        float hy = sqrtf(MAHA_T * c11) * 1.01f + 0.01f;
        float hz = sqrtf(MAHA_T * c22) * 1.01f + 0.01f;
        bool hit = (mx - hx <= x1) && (mx + hx >= x0) &&
                   (my - hy <= y1) && (my + hy >= y0) &&
                   (mz - hz <= 5.4f) && (mz + hz >= -1.0f);
        unsigned long long m = __ballot(hit);
        int rank = __popcll(m & ((1ull << lane) - 1ull));
        if (hit) s_stage[wave * 128 + base + rank] = (unsigned short)g;
        base += __popcll(m);
    }
    if (lane == 0) s_wcnt[wave] = base;
    __syncthreads();
    int total = 0, off = 0;
#pragma unroll
    for (int w2 = 0; w2 < 8; ++w2) {
        int c = s_wcnt[w2];
        if (w2 < wave) off += c;
        total += c;
    }
    for (int i = lane; i < base; i += 64)          // wave-local segment copy
        s_list[off + i] = s_stage[wave * 128 + i]; // globally ascending-g order

    // ---- Voxels owned by this thread ----
    const int z = lane & 15;
    const int yv = lane >> 4;            // 0..3
    const int X = bx * 8 + wave;
    const int Y0 = by * 8 + yv;          // second voxel at Y0+4

    float cx, cy0, cy1, cz;
    {
#pragma clang fp contract(off)   // bit-match ref: separate mul/add rounding
        cx  = ((float)X + 0.5f) * 0.4f + -40.0f;
        cy0 = ((float)Y0 + 0.5f) * 0.4f + -40.0f;
        cy1 = ((float)(Y0 + 4) + 0.5f) * 0.4f + -40.0f;
        cz  = ((float)z + 0.5f) * 0.4f + -1.0f;
    }

    float ds0 = 0.f, ds1 = 0.f, cn0 = 0.f, cn1 = 0.f;
    float f0[C_N], f1[C_N];
#pragma unroll
    for (int c = 0; c < C_N; ++c) { f0[c] = 0.f; f1[c] = 0.f; }

    // ---- Phase 2: stage survivors (fp64 inversion in-block) + main loop ----
    float4* s_gd = (float4*)smemA;
    for (int cb = 0; cb < total; cb += CAP) {
        const int nc = min(CAP, total - cb);
        __syncthreads();                 // region A free
        if (tid < nc) {                  // one thread per candidate
            int g = (int)s_list[cb + tid];
            const float* cv = covs + g * 9;
            double c00 = cv[0], c01 = cv[1], c02 = cv[2];
            double c11 = cv[4], c12 = cv[5], c22 = cv[8];
            double m00 = c11 * c22 - c12 * c12;
            double m01 = c02 * c12 - c01 * c22;
            double m02 = c01 * c12 - c02 * c11;
            double det = c00 * m00 + c01 * m01 + c02 * m02;
            double inv = 1.0 / det;
            float a00 = (float)(m00 * inv);
            float a01 = (float)(m01 * inv);
            float a02 = (float)(m02 * inv);
            float a11 = (float)((c00 * c22 - c02 * c02) * inv);
            float a12 = (float)((c02 * c01 - c00 * c12) * inv);
            float a22 = (float)((c00 * c11 - c01 * c01) * inv);
            float mx = means[3 * g], my = means[3 * g + 1], mz = means[3 * g + 2];
            float op = ops[g];
            const float* ft = feats + g * C_N;
            float4* o = s_gd + tid * 8;
            o[0] = make_float4(mx, my, mz, op);
            o[1] = make_float4(a00, a11, a22, 2.f * a01);
            o[2] = make_float4(2.f * a02, 2.f * a12, op * ft[0], op * ft[1]);
            o[3] = make_float4(op * ft[2], op * ft[3], op * ft[4], op * ft[5]);
            o[4] = make_float4(op * ft[6], op * ft[7], op * ft[8], op * ft[9]);
            o[5] = make_float4(op * ft[10], op * ft[11], op * ft[12], op * ft[13]);
            o[6] = make_float4(op * ft[14], op * ft[15], op * ft[16], 0.f);
        }
        __syncthreads();
        for (int j = 0; j < nc; ++j) {
            const float4* rowp = s_gd + j * 8;
            float4 q0 = rowp[0], q1 = rowp[1], q2 = rowp[2];
            float d0 = cx - q0.x, d2 = cz - q0.z;
            float d1a = cy0 - q0.y, d1b = cy1 - q0.y;
            // shared subterms (each voxel's rounding identical to R3 formula)
            float s1 = q2.x * d2;        // (2a02)*d2
            float s2 = q2.y * d2;        // (2a12)*d2
            float w  = q1.z * d2;        // a22*d2
            float sw = d2 * w;
            float u0 = fmaf(q1.x, d0, fmaf(q1.w, d1a, s1));
            float u1 = fmaf(q1.x, d0, fmaf(q1.w, d1b, s1));
            float v0 = fmaf(q1.y, d1a, s2);
            float v1 = fmaf(q1.y, d1b, s2);
            float maha0 = fmaf(d0, u0, fmaf(d1a, v0, sw));
            float maha1 = fmaf(d0, u1, fmaf(d1b, v1, sw));
            bool h0 = maha0 <= MAHA_T, h1 = maha1 <= MAHA_T;
            if (h0 || h1) {
                float4 q3 = rowp[3], q4 = rowp[4], q5 = rowp[5], q6 = rowp[6];
                if (h0) {
                    ds0 = fmaf(q0.w, __expf(-0.5f * maha0), ds0); cn0 += 1.f;
                    f0[0] += q2.z;  f0[1] += q2.w;
                    f0[2] += q3.x;  f0[3] += q3.y;  f0[4] += q3.z;  f0[5] += q3.w;
                    f0[6] += q4.x;  f0[7] += q4.y;  f0[8] += q4.z;  f0[9] += q4.w;
                    f0[10] += q5.x; f0[11] += q5.y; f0[12] += q5.z; f0[13] += q5.w;
                    f0[14] += q6.x; f0[15] += q6.y; f0[16] += q6.z;
                }
                if (h1) {
                    ds1 = fmaf(q0.w, __expf(-0.5f * maha1), ds1); cn1 += 1.f;
                    f1[0] += q2.z;  f1[1] += q2.w;
                    f1[2] += q3.x;  f1[3] += q3.y;  f1[4] += q3.z;  f1[5] += q3.w;
                    f1[6] += q4.x;  f1[7] += q4.y;  f1[8] += q4.z;  f1[9] += q4.w;
                    f1[10] += q5.x; f1[11] += q5.y; f1[12] += q5.z; f1[13] += q5.w;
                    f1[14] += q6.x; f1[15] += q6.y; f1[16] += q6.z;
                }
            }
        }
    }
    __syncthreads();   // all main-loop LDS reads done before out-stage reuse

    // ---- Phase 3: coalesced epilogue (wave-local, two passes) ----
    const long n00 = (long)128 * by + (long)3200 * X;   // first voxel of wave span
    const float rd0 = 1.f / fmaxf(cn0, 1.f);
    const float rd1 = 1.f / fmaxf(cn1, 1.f);
    dens_out[n00 + lane] = ds0 * rd0;
    dens_out[n00 + 64 + lane] = ds1 * rd1;

    float* fw = (float*)(smemA + wave * (64 * C_N * 4));
    const float4* lsrc = (const float4*)fw;
    // pass 0: voxels [n00, n00+64)
#pragma unroll
    for (int c = 0; c < C_N; ++c) fw[lane * C_N + c] = f0[c] * rd0;
    float4* gout0 = (float4*)(feat_out + n00 * C_N);
#pragma unroll
    for (int r = 0; r < 4; ++r) gout0[lane + 64 * r] = lsrc[lane + 64 * r];
    if (lane < 16) gout0[256 + lane] = lsrc[256 + lane];
    // pass 1: voxels [n00+64, n00+128)  (same-wave LDS ops are in-order)
#pragma unroll
    for (int c = 0; c < C_N; ++c) fw[lane * C_N + c] = f1[c] * rd1;
    float4* gout1 = (float4*)(feat_out + (n00 + 64) * C_N);
#pragma unroll
    for (int r = 0; r < 4; ++r) gout1[lane + 64 * r] = lsrc[lane + 64 * r];
    if (lane < 16) gout1[256 + lane] = lsrc[256 + lane];
}

extern "C" void kernel_launch(void* const* d_in, const int* in_sizes, int n_in,
                              void* d_out, int out_size, void* d_ws, size_t ws_size,
                              hipStream_t stream) {
    const float* means3d     = (const float*)d_in[1];  // [1,G,3]
    const float* opacities   = (const float*)d_in[2];  // [1,G,1]
    const float* features    = (const float*)d_in[3];  // [1,G,C]
    const float* covariances = (const float*)d_in[4];  // [1,G,3,3]

    float* dens_out = (float*)d_out;             // [N]
    float* feat_out = (float*)d_out + N_VOX;     // [N,C]

    dim3 grid(NX / 8, NY / 8);
    gv_fused_kernel<<<grid, 512, 0, stream>>>(means3d, opacities, features,
                                              covariances, dens_out, feat_out);
}